// Round 1
// baseline (230.792 us; speedup 1.0000x reference)
//
#include <hip/hip_runtime.h>
#include <hip/hip_bf16.h>

typedef unsigned short u16;
typedef __attribute__((ext_vector_type(8))) short short8;
typedef __attribute__((ext_vector_type(4))) float f32x4;

constexpr int N = 8192;
constexpr int D = 1024;
constexpr float INVT = 1.0f / 0.07f;

// ---- workspace layout (bytes) ----
constexpr size_t OFF_FBF  = 0;                       // N*D bf16 = 16 MiB
constexpr size_t OFF_SUME = 16777216;                // N f32 (32 KiB)
constexpr size_t OFF_POSS = OFF_SUME + 32768;        // N f32 (32 KiB)
constexpr size_t OFF_HIST = OFF_POSS + 32768;        // 32 i32 (pad 128)
constexpr size_t OFF_TYPE = OFF_HIST + 128;          // N i32 (32 KiB)
constexpr int ZERO_WORDS = (32768 + 32768 + 128) / 4;  // sum_exp+pos_sum+hist

__global__ __launch_bounds__(256) void k_zero(float* __restrict__ p, int n) {
  int i = blockIdx.x * 256 + threadIdx.x;
  if (i < n) p[i] = 0.0f;
}

__device__ __forceinline__ u16 f2bf(float f) {
  __hip_bfloat16 h = __float2bfloat16(f);
  union { __hip_bfloat16 h; u16 u; } cv; cv.h = h; return cv.u;
}

// normalize one row per block (256 thr x 4 f32), emit bf16; type histogram
__global__ __launch_bounds__(256) void k_norm(
    const float* __restrict__ feat, const long long* __restrict__ et,
    u16* __restrict__ fbf, int* __restrict__ types, int* __restrict__ hist) {
  const int row = blockIdx.x;
  const int t = threadIdx.x;
  const float4 v = *(const float4*)(feat + (size_t)row * D + t * 4);
  float ss = v.x * v.x + v.y * v.y + v.z * v.z + v.w * v.w;
  #pragma unroll
  for (int m = 32; m; m >>= 1) ss += __shfl_xor(ss, m);
  __shared__ float wsum[4];
  if ((t & 63) == 0) wsum[t >> 6] = ss;
  __syncthreads();
  const float tot = wsum[0] + wsum[1] + wsum[2] + wsum[3];
  const float sc = 1.0f / fmaxf(sqrtf(tot), 1e-12f);
  ushort4 o;
  o.x = f2bf(v.x * sc); o.y = f2bf(v.y * sc);
  o.z = f2bf(v.z * sc); o.w = f2bf(v.w * sc);
  *(ushort4*)(fbf + (size_t)row * D + t * 4) = o;
  if (t == 0) {
    int ty = (int)et[row];
    types[row] = ty;
    atomicAdd(&hist[ty], 1);
  }
}

__device__ __forceinline__ void async_ld16(const u16* g, u16* l) {
  __builtin_amdgcn_global_load_lds(
      (const __attribute__((address_space(1))) void*)g,
      (__attribute__((address_space(3))) void*)l, 16, 0, 0);
}

__device__ __forceinline__ void mfma16(f32x4& d, short8 a, short8 b) {
  asm volatile("v_mfma_f32_16x16x32_bf16 %0, %1, %2, %0"
               : "+v"(d) : "v"(a), "v"(b));
}

// 128x128 tile of sim = fbf * fbf^T / T, fused exp/mask row-reductions.
// 4 waves (2x2), each wave 64x64 via 4x4 frags of 16x16x32 MFMA. BK=32.
__global__ __launch_bounds__(256) void k_gemm(
    const u16* __restrict__ fbf, const int* __restrict__ types,
    float* __restrict__ sum_exp, float* __restrict__ pos_sum) {
  __shared__ u16 As[128 * 32];
  __shared__ u16 Bs[128 * 32];
  __shared__ int rt[128], ct[128];

  // bijective XCD swizzle (4096 % 8 == 0) + 8-row grouping:
  // each XCD owns one 8-rowblock group -> 8 A-panels (2 MB) L2-resident.
  const int pid = blockIdx.x;
  const int x = (pid & 7) * 512 + (pid >> 3);
  const int rb = (x >> 9) * 8 + (x & 7);
  const int cb = (x & 511) >> 3;
  const int brow = rb * 128, bcol = cb * 128;

  const int tid = threadIdx.x;
  const int lane = tid & 63;
  const int wid = tid >> 6;
  const int wr = wid >> 1, wc = wid & 1;

  if (tid < 128) rt[tid] = types[brow + tid];
  else           ct[tid - 128] = types[bcol + tid - 128];

  f32x4 acc[4][4];
  #pragma unroll
  for (int i = 0; i < 4; ++i)
    #pragma unroll
    for (int j = 0; j < 4; ++j) acc[i][j] = (f32x4){0.f, 0.f, 0.f, 0.f};

  // staging: idx = it*256 + tid covers 128x32 bf16, 8 contiguous per thread
  const int srow = tid >> 2;          // 0..63
  const int scol = (tid & 3) * 8;     // 0,8,16,24
  const u16* ga0 = fbf + (size_t)(brow + srow) * D + scol;
  const u16* ga1 = fbf + (size_t)(brow + 64 + srow) * D + scol;
  const u16* gb0 = fbf + (size_t)(bcol + srow) * D + scol;
  const u16* gb1 = fbf + (size_t)(bcol + 64 + srow) * D + scol;
  // wave-uniform LDS bases (global_load_lds writes base + lane*16B)
  u16* lA0 = &As[(tid & ~63) * 8];
  u16* lA1 = &As[2048 + (tid & ~63) * 8];
  u16* lB0 = &Bs[(tid & ~63) * 8];
  u16* lB1 = &Bs[2048 + (tid & ~63) * 8];

  const int aoff = (wr * 64 + (lane & 15)) * 32 + (lane >> 4) * 8;
  const int boff = (wc * 64 + (lane & 15)) * 32 + (lane >> 4) * 8;

  for (int ko = 0; ko < D; ko += 32) {
    async_ld16(ga0 + ko, lA0);
    async_ld16(ga1 + ko, lA1);
    async_ld16(gb0 + ko, lB0);
    async_ld16(gb1 + ko, lB1);
    __syncthreads();   // compiler drains vmcnt before s_barrier
    short8 a[4], b[4];
    #pragma unroll
    for (int mi = 0; mi < 4; ++mi) a[mi] = *(const short8*)&As[aoff + mi * 512];
    #pragma unroll
    for (int ni = 0; ni < 4; ++ni) b[ni] = *(const short8*)&Bs[boff + ni * 512];
    #pragma unroll
    for (int mi = 0; mi < 4; ++mi)
      #pragma unroll
      for (int ni = 0; ni < 4; ++ni) mfma16(acc[mi][ni], a[mi], b[ni]);
    __syncthreads();
  }

  // MFMA -> VALU read hazard guard (inline-asm MFMA is opaque to the
  // hazard recognizer); empty volatile asms anchor acc reads after nops.
  asm volatile("s_nop 7\n\ts_nop 7\n\ts_nop 7");
  #pragma unroll
  for (int i = 0; i < 4; ++i)
    #pragma unroll
    for (int j = 0; j < 4; ++j) asm volatile("" : "+v"(acc[i][j]));

  // epilogue: C/D layout col = lane&15, row = (lane>>4)*4 + reg  [m89]
  const int csub = lane & 15;
  const int rsub = (lane >> 4) * 4;
  int gcolv[4], ctv[4];
  #pragma unroll
  for (int ni = 0; ni < 4; ++ni) {
    const int cl = wc * 64 + ni * 16 + csub;
    gcolv[ni] = bcol + cl;
    ctv[ni] = ct[cl];
  }
  #pragma unroll
  for (int mi = 0; mi < 4; ++mi) {
    #pragma unroll
    for (int r = 0; r < 4; ++r) {
      const int rl = wr * 64 + mi * 16 + rsub + r;
      const int grow = brow + rl;
      const int rty = rt[rl];
      float se = 0.f, ps = 0.f;
      #pragma unroll
      for (int ni = 0; ni < 4; ++ni) {
        const float s = acc[mi][ni][r] * INVT;
        if (gcolv[ni] != grow) {          // exclude diagonal
          se += __expf(s);
          if (ctv[ni] == rty) ps += s;    // positives: same type, j != i
        }
      }
      #pragma unroll
      for (int m = 8; m; m >>= 1) {       // reduce across 16 cols (one group)
        se += __shfl_xor(se, m);
        ps += __shfl_xor(ps, m);
      }
      if (csub == 0) {
        atomicAdd(&sum_exp[grow], se);
        atomicAdd(&pos_sum[grow], ps);
      }
    }
  }
}

__global__ __launch_bounds__(1024) void k_final(
    const float* __restrict__ sum_exp, const float* __restrict__ pos_sum,
    const int* __restrict__ types, const int* __restrict__ hist,
    float* __restrict__ out) {
  const int t = threadIdx.x;
  float ls = 0.f, cnt = 0.f;
  for (int r = t; r < N; r += 1024) {
    const int pc = hist[types[r]] - 1;
    if (pc > 0) {
      const float pm = pos_sum[r] / (float)pc;
      ls += -logf(__expf(pm) / sum_exp[r] + 1e-10f);
      cnt += 1.f;
    }
  }
  #pragma unroll
  for (int m = 32; m; m >>= 1) {
    ls += __shfl_xor(ls, m);
    cnt += __shfl_xor(cnt, m);
  }
  __shared__ float s1[16], s2[16];
  if ((t & 63) == 0) { s1[t >> 6] = ls; s2[t >> 6] = cnt; }
  __syncthreads();
  if (t == 0) {
    float T = 0.f, C = 0.f;
    for (int i = 0; i < 16; ++i) { T += s1[i]; C += s2[i]; }
    out[0] = (C > 0.f) ? T / C : 0.f;
  }
}

extern "C" void kernel_launch(void* const* d_in, const int* in_sizes, int n_in,
                              void* d_out, int out_size, void* d_ws, size_t ws_size,
                              hipStream_t stream) {
  const float* feat = (const float*)d_in[0];
  const long long* et = (const long long*)d_in[1];
  char* ws = (char*)d_ws;
  u16* fbf      = (u16*)(ws + OFF_FBF);
  float* sum_e  = (float*)(ws + OFF_SUME);
  float* pos_s  = (float*)(ws + OFF_POSS);
  int* hist     = (int*)(ws + OFF_HIST);
  int* types    = (int*)(ws + OFF_TYPE);
  float* out    = (float*)d_out;

  k_zero<<<(ZERO_WORDS + 255) / 256, 256, 0, stream>>>(sum_e, ZERO_WORDS);
  k_norm<<<N, 256, 0, stream>>>(feat, et, fbf, types, hist);
  k_gemm<<<4096, 256, 0, stream>>>(fbf, types, sum_e, pos_s);
  k_final<<<1, 1024, 0, stream>>>(sum_e, pos_s, types, hist, out);
}

// Round 2
// 201.887 us; speedup vs baseline: 1.1432x; 1.1432x over previous
//
#include <hip/hip_runtime.h>
#include <hip/hip_bf16.h>

typedef unsigned short u16;
typedef __attribute__((ext_vector_type(8))) short short8;
typedef __attribute__((ext_vector_type(4))) float f32x4;

constexpr int N = 8192;
constexpr int D = 1024;
constexpr float INVT = 1.0f / 0.07f;
constexpr int NBLK = 64;                       // 8192 / 128 row-blocks
constexpr int NTRI = NBLK * (NBLK + 1) / 2;    // 2080 lower-tri tiles (8 | 2080)

// ---- workspace layout (bytes) ----
constexpr size_t OFF_FBF  = 0;                       // N*D bf16 = 16 MiB
constexpr size_t OFF_SUME = 16777216;                // N f32 (32 KiB)
constexpr size_t OFF_POSS = OFF_SUME + 32768;        // N f32 (32 KiB)
constexpr size_t OFF_HIST = OFF_POSS + 32768;        // 32 i32 (pad 128)
constexpr size_t OFF_TYPE = OFF_HIST + 128;          // N i32 (32 KiB)
constexpr int ZERO_WORDS = (32768 + 32768 + 128) / 4;  // sum_exp+pos_sum+hist

__global__ __launch_bounds__(256) void k_zero(float* __restrict__ p, int n) {
  int i = blockIdx.x * 256 + threadIdx.x;
  if (i < n) p[i] = 0.0f;
}

__device__ __forceinline__ u16 f2bf(float f) {
  __hip_bfloat16 h = __float2bfloat16(f);
  union { __hip_bfloat16 h; u16 u; } cv; cv.h = h; return cv.u;
}

// normalize one row per block (256 thr x 4 f32), emit bf16; type histogram
__global__ __launch_bounds__(256) void k_norm(
    const float* __restrict__ feat, const long long* __restrict__ et,
    u16* __restrict__ fbf, int* __restrict__ types, int* __restrict__ hist) {
  const int row = blockIdx.x;
  const int t = threadIdx.x;
  const float4 v = *(const float4*)(feat + (size_t)row * D + t * 4);
  float ss = v.x * v.x + v.y * v.y + v.z * v.z + v.w * v.w;
  #pragma unroll
  for (int m = 32; m; m >>= 1) ss += __shfl_xor(ss, m);
  __shared__ float wsum[4];
  if ((t & 63) == 0) wsum[t >> 6] = ss;
  __syncthreads();
  const float tot = wsum[0] + wsum[1] + wsum[2] + wsum[3];
  const float sc = 1.0f / fmaxf(sqrtf(tot), 1e-12f);
  ushort4 o;
  o.x = f2bf(v.x * sc); o.y = f2bf(v.y * sc);
  o.z = f2bf(v.z * sc); o.w = f2bf(v.w * sc);
  *(ushort4*)(fbf + (size_t)row * D + t * 4) = o;
  if (t == 0) {
    int ty = (int)et[row];
    types[row] = ty;
    atomicAdd(&hist[ty], 1);
  }
}

__device__ __forceinline__ void async_ld16(const u16* g, u16* l) {
  __builtin_amdgcn_global_load_lds(
      (const __attribute__((address_space(1))) void*)g,
      (__attribute__((address_space(3))) void*)l, 16, 0, 0);
}

__device__ __forceinline__ void mfma16(f32x4& d, short8 a, short8 b) {
  asm volatile("v_mfma_f32_16x16x32_bf16 %0, %1, %2, %0"
               : "+v"(d) : "v"(a), "v"(b));
}

// Lower-triangular 128x128 tiles of sim = fbf * fbf^T / T (symmetric!).
// Off-diagonal tiles contribute BOTH row-sums (rows of rb-block) and, via
// transpose symmetry, row-sums for the cb-block (= column reductions).
// 4 waves (2x2), each wave 64x64 via 4x4 frags of 16x16x32 MFMA. BK=32.
__global__ __launch_bounds__(256) void k_gemm(
    const u16* __restrict__ fbf, const int* __restrict__ types,
    float* __restrict__ sum_exp, float* __restrict__ pos_sum) {
  __shared__ u16 As[128 * 32];
  __shared__ u16 Bs[128 * 32];
  __shared__ int rt[128], ct[128];

  // bijective XCD swizzle (2080 % 8 == 0): 260 consecutive tri-tiles per XCD;
  // consecutive pids share the rb A-panel -> L2 reuse.
  const int pid = blockIdx.x;
  const int x = (pid & 7) * (NTRI / 8) + (pid >> 3);
  // triangular decode: x = rb*(rb+1)/2 + cb, 0 <= cb <= rb
  int rb = (int)((sqrtf(8.0f * (float)x + 1.0f) - 1.0f) * 0.5f);
  while ((rb + 1) * (rb + 2) / 2 <= x) ++rb;
  while (rb * (rb + 1) / 2 > x) --rb;
  const int cb = x - rb * (rb + 1) / 2;
  const int brow = rb * 128, bcol = cb * 128;
  const bool diag = (rb == cb);

  const int tid = threadIdx.x;
  const int lane = tid & 63;
  const int wid = tid >> 6;
  const int wr = wid >> 1, wc = wid & 1;

  if (tid < 128) rt[tid] = types[brow + tid];
  else           ct[tid - 128] = types[bcol + tid - 128];

  f32x4 acc[4][4];
  #pragma unroll
  for (int i = 0; i < 4; ++i)
    #pragma unroll
    for (int j = 0; j < 4; ++j) acc[i][j] = (f32x4){0.f, 0.f, 0.f, 0.f};

  // staging: 128x32 bf16 per matrix per K-step, 8 contiguous bf16 per thread
  const int srow = tid >> 2;          // 0..63
  const int scol = (tid & 3) * 8;     // 0,8,16,24
  const u16* ga0 = fbf + (size_t)(brow + srow) * D + scol;
  const u16* ga1 = fbf + (size_t)(brow + 64 + srow) * D + scol;
  const u16* gb0 = fbf + (size_t)(bcol + srow) * D + scol;
  const u16* gb1 = fbf + (size_t)(bcol + 64 + srow) * D + scol;
  // wave-uniform LDS bases (global_load_lds writes base + lane*16B)
  u16* lA0 = &As[(tid & ~63) * 8];
  u16* lA1 = &As[2048 + (tid & ~63) * 8];
  u16* lB0 = &Bs[(tid & ~63) * 8];
  u16* lB1 = &Bs[2048 + (tid & ~63) * 8];

  const int aoff = (wr * 64 + (lane & 15)) * 32 + (lane >> 4) * 8;
  const int boff = (wc * 64 + (lane & 15)) * 32 + (lane >> 4) * 8;

  for (int ko = 0; ko < D; ko += 32) {
    async_ld16(ga0 + ko, lA0);
    async_ld16(ga1 + ko, lA1);
    async_ld16(gb0 + ko, lB0);
    async_ld16(gb1 + ko, lB1);
    __syncthreads();   // compiler drains vmcnt before s_barrier
    short8 a[4], b[4];
    #pragma unroll
    for (int mi = 0; mi < 4; ++mi) a[mi] = *(const short8*)&As[aoff + mi * 512];
    #pragma unroll
    for (int ni = 0; ni < 4; ++ni) b[ni] = *(const short8*)&Bs[boff + ni * 512];
    #pragma unroll
    for (int mi = 0; mi < 4; ++mi)
      #pragma unroll
      for (int ni = 0; ni < 4; ++ni) mfma16(acc[mi][ni], a[mi], b[ni]);
    __syncthreads();
  }

  // MFMA -> VALU read hazard guard (inline-asm MFMA is opaque to the
  // hazard recognizer); empty volatile asms anchor acc reads after nops.
  asm volatile("s_nop 7\n\ts_nop 7\n\ts_nop 7");
  #pragma unroll
  for (int i = 0; i < 4; ++i)
    #pragma unroll
    for (int j = 0; j < 4; ++j) asm volatile("" : "+v"(acc[i][j]));

  // epilogue: C/D layout col = lane&15, row = (lane>>4)*4 + reg  [m89]
  const int csub = lane & 15;
  const int rsub = (lane >> 4) * 4;
  int gcolv[4], ctv[4];
  #pragma unroll
  for (int ni = 0; ni < 4; ++ni) {
    const int cl = wc * 64 + ni * 16 + csub;
    gcolv[ni] = bcol + cl;
    ctv[ni] = ct[cl];
  }
  // column partials (transpose contributions), accumulated across (mi,r)
  float cse[4] = {0.f, 0.f, 0.f, 0.f};
  float cps[4] = {0.f, 0.f, 0.f, 0.f};

  #pragma unroll
  for (int mi = 0; mi < 4; ++mi) {
    #pragma unroll
    for (int r = 0; r < 4; ++r) {
      const int rl = wr * 64 + mi * 16 + rsub + r;
      const int grow = brow + rl;
      const int rty = rt[rl];
      float se = 0.f, ps = 0.f;
      #pragma unroll
      for (int ni = 0; ni < 4; ++ni) {
        const float s = acc[mi][ni][r] * INVT;
        const float e = __expf(s);
        const bool match = (ctv[ni] == rty);
        if (diag) {
          if (gcolv[ni] != grow) { se += e; if (match) ps += s; }
        } else {
          se += e; if (match) ps += s;
          cse[ni] += e; if (match) cps[ni] += s;   // transpose -> row gcolv[ni]
        }
      }
      #pragma unroll
      for (int m = 8; m; m >>= 1) {       // reduce across 16 cols (one group)
        se += __shfl_xor(se, m);
        ps += __shfl_xor(ps, m);
      }
      if (csub == 0) {
        atomicAdd(&sum_exp[grow], se);
        atomicAdd(&pos_sum[grow], ps);
      }
    }
  }

  if (!diag) {
    #pragma unroll
    for (int ni = 0; ni < 4; ++ni) {
      float se = cse[ni], ps = cps[ni];
      se += __shfl_xor(se, 16); se += __shfl_xor(se, 32);
      ps += __shfl_xor(ps, 16); ps += __shfl_xor(ps, 32);
      if (lane < 16) {                    // one lane per column (csub 0..15)
        atomicAdd(&sum_exp[gcolv[ni]], se);
        atomicAdd(&pos_sum[gcolv[ni]], ps);
      }
    }
  }
}

__global__ __launch_bounds__(1024) void k_final(
    const float* __restrict__ sum_exp, const float* __restrict__ pos_sum,
    const int* __restrict__ types, const int* __restrict__ hist,
    float* __restrict__ out) {
  const int t = threadIdx.x;
  float ls = 0.f, cnt = 0.f;
  for (int r = t; r < N; r += 1024) {
    const int pc = hist[types[r]] - 1;
    if (pc > 0) {
      const float pm = pos_sum[r] / (float)pc;
      ls += -logf(__expf(pm) / sum_exp[r] + 1e-10f);
      cnt += 1.f;
    }
  }
  #pragma unroll
  for (int m = 32; m; m >>= 1) {
    ls += __shfl_xor(ls, m);
    cnt += __shfl_xor(cnt, m);
  }
  __shared__ float s1[16], s2[16];
  if ((t & 63) == 0) { s1[t >> 6] = ls; s2[t >> 6] = cnt; }
  __syncthreads();
  if (t == 0) {
    float T = 0.f, C = 0.f;
    for (int i = 0; i < 16; ++i) { T += s1[i]; C += s2[i]; }
    out[0] = (C > 0.f) ? T / C : 0.f;
  }
}

extern "C" void kernel_launch(void* const* d_in, const int* in_sizes, int n_in,
                              void* d_out, int out_size, void* d_ws, size_t ws_size,
                              hipStream_t stream) {
  const float* feat = (const float*)d_in[0];
  const long long* et = (const long long*)d_in[1];
  char* ws = (char*)d_ws;
  u16* fbf      = (u16*)(ws + OFF_FBF);
  float* sum_e  = (float*)(ws + OFF_SUME);
  float* pos_s  = (float*)(ws + OFF_POSS);
  int* hist     = (int*)(ws + OFF_HIST);
  int* types    = (int*)(ws + OFF_TYPE);
  float* out    = (float*)d_out;

  k_zero<<<(ZERO_WORDS + 255) / 256, 256, 0, stream>>>(sum_e, ZERO_WORDS);
  k_norm<<<N, 256, 0, stream>>>(feat, et, fbf, types, hist);
  k_gemm<<<NTRI, 256, 0, stream>>>(fbf, types, sum_e, pos_s);
  k_final<<<1, 1024, 0, stream>>>(sum_e, pos_s, types, hist, out);
}